// Round 2
// baseline (59.578 us; speedup 1.0000x reference)
//
#include <hip/hip_runtime.h>

// GlobalConvolutionalLayer: out[n,c,m] = 0.5*xi_eff[c]*dx * sum_l d[n,l]*exp(-|x_l-x_m|*xi_eff[c])
// Separable exponential kernel on sorted uniform grid -> prefix/suffix scans, O(G) per (n,c).
// Two-phase for parallelism: (1) per-segment partial sums -> ws, (2) local scan + offsets.
// xi_eff = 1/sigmoid(xi) = 1 + exp(-xi) in (1.37, 2]; exp(x*xi_eff) <= e^2, no overflow.

#define GG 4096
#define CC 8
#define NN 4
#define SS 16            // segments per (n,c) row
#define SEG (GG / SS)    // 256 elements per segment
#define BLOCK 256        // 1 element per thread

// ws layout: sumA[NN*CC*SS] then sumB[NN*CC*SS]  (4 KB total)

__global__ __launch_bounds__(BLOCK) void gconv_partials(const float* __restrict__ density,
                                                        const float* __restrict__ xi,
                                                        const float* __restrict__ grid,
                                                        float* __restrict__ ws) {
    const int bid = blockIdx.x;                 // ((n*CC + c)*SS + s)
    const int s   = bid & (SS - 1);
    const int c   = (bid >> 4) & (CC - 1);
    const int n   = bid >> 7;
    const int tid = threadIdx.x;
    const int m   = s * SEG + tid;

    const float k  = 1.0f + __expf(-xi[c]);
    const float x  = grid[m];
    const float d  = density[n * GG + m];
    const float ea = __expf(x * k);
    const float eb = __expf(-x * k);
    float a = d * ea;
    float b = d * eb;

#pragma unroll
    for (int off = 32; off >= 1; off >>= 1) {
        a += __shfl_xor(a, off, 64);
        b += __shfl_xor(b, off, 64);
    }

    __shared__ float lA[BLOCK / 64];
    __shared__ float lB[BLOCK / 64];
    const int wave = tid >> 6;
    if ((tid & 63) == 0) { lA[wave] = a; lB[wave] = b; }
    __syncthreads();
    if (tid == 0) {
        float tA = 0.0f, tB = 0.0f;
#pragma unroll
        for (int w = 0; w < BLOCK / 64; ++w) { tA += lA[w]; tB += lB[w]; }
        ws[bid] = tA;
        ws[NN * CC * SS + bid] = tB;
    }
}

__global__ __launch_bounds__(BLOCK) void gconv_finalize(const float* __restrict__ density,
                                                        const float* __restrict__ xi,
                                                        const float* __restrict__ grid,
                                                        const float* __restrict__ ws,
                                                        float* __restrict__ out) {
    const int bid = blockIdx.x;
    const int s   = bid & (SS - 1);
    const int c   = (bid >> 4) & (CC - 1);
    const int n   = bid >> 7;
    const int tid = threadIdx.x;
    const int m   = s * SEG + tid;

    const float k  = 1.0f + __expf(-xi[c]);
    const float dx = grid[1] - grid[0];
    const float x  = grid[m];
    const float d  = density[n * GG + m];
    const float ea = __expf(x * k);     // identical expressions to kernel1 -> consistent values
    const float eb = __expf(-x * k);
    const float a = d * ea;
    const float b = d * eb;

    // inclusive scan across the block (wave shfl_up scan + LDS wave combine)
    float sA = a, sB = b;
#pragma unroll
    for (int off = 1; off < 64; off <<= 1) {
        const float tA = __shfl_up(sA, off, 64);
        const float tB = __shfl_up(sB, off, 64);
        if ((tid & 63) >= off) { sA += tA; sB += tB; }
    }
    __shared__ float wA[BLOCK / 64];
    __shared__ float wB[BLOCK / 64];
    const int wave = tid >> 6;
    if ((tid & 63) == 63) { wA[wave] = sA; wB[wave] = sB; }
    __syncthreads();

    float preA = 0.0f, preB = 0.0f, totB = 0.0f;
#pragma unroll
    for (int w = 0; w < BLOCK / 64; ++w) {
        const float ta = wA[w];
        const float tb = wB[w];
        if (w < wave) { preA += ta; preB += tb; }
        totB += tb;
    }
    const float pA   = preA + sA;           // inclusive prefix of a within segment
    const float sufB = totB - (preB + sB);  // exclusive suffix of b within segment

    // cross-segment offsets from partials (uniform scalar loads, L2-resident)
    const float* __restrict__ sumA = ws + (bid - s);             // row base: (n*CC+c)*SS
    const float* __restrict__ sumB = ws + NN * CC * SS + (bid - s);
    float offA = 0.0f, offB = 0.0f;
#pragma unroll
    for (int sp = 0; sp < SS; ++sp) {
        const float vA = sumA[sp];
        const float vB = sumB[sp];
        if (sp < s) offA += vA;
        if (sp > s) offB += vB;
    }

    const float scale = 0.5f * k * dx;
    out[(n * CC + c) * GG + m] = scale * (eb * (offA + pA) + ea * (offB + sufB));
}

extern "C" void kernel_launch(void* const* d_in, const int* in_sizes, int n_in,
                              void* d_out, int out_size, void* d_ws, size_t ws_size,
                              hipStream_t stream) {
    const float* density = (const float*)d_in[0];  // (N,1,G) fp32
    const float* xi      = (const float*)d_in[1];  // (C,)    fp32
    const float* grid    = (const float*)d_in[2];  // (G,)    fp32
    float* out           = (float*)d_out;          // (N,C,G) fp32
    float* ws            = (float*)d_ws;           // 4 KB partials

    gconv_partials<<<NN * CC * SS, BLOCK, 0, stream>>>(density, xi, grid, ws);
    gconv_finalize<<<NN * CC * SS, BLOCK, 0, stream>>>(density, xi, grid, ws, out);
}